// Round 6
// baseline (444.625 us; speedup 1.0000x reference)
//
#include <hip/hip_runtime.h>
#include <hip/hip_bf16.h>

#define D 128
#define NK 16
#define BT (64*2048)

typedef short bf16x8 __attribute__((ext_vector_type(8)));
typedef float f32x4 __attribute__((ext_vector_type(4)));

__device__ __forceinline__ unsigned short f2bf(float f) {
  unsigned u = __builtin_bit_cast(unsigned, f);
  unsigned r = (u + 0x7FFFu + ((u >> 16) & 1u)) >> 16;   // round-to-nearest-even
  return (unsigned short)r;
}
__device__ __forceinline__ float bf2f(unsigned short h) {
  unsigned u = ((unsigned)h) << 16;
  return __builtin_bit_cast(float, u);
}

// ---------------- Setup ----------------
// R5 lesson: ANY per-column LDS round-trips serialize at ~3-4x single-wave latency under
// multi-wave contention; 128 cols x 2 phases was ~200us no matter how the update was coded.
// R6: rows live in REGISTERS (thread r owns row r, float4 a[32], fully unrolled -> static
// indices). Per column step: broadcast-read the (unscaled) pivot column from a double-buffered
// cb, FMA in registers, publish next column, ONE barrier. LDL-form: update uses 1/d; final
// L[r][c] = a[c]*rsqrt(d_c) applied once at the end. logdet = 0.5*sum log d.
__global__ __launch_bounds__(128, 1) void setup_kernel(const float* __restrict__ sigma,
                                                       const float* __restrict__ mu,
                                                       unsigned short* __restrict__ WG,
                                                       float* __restrict__ LmuG,
                                                       float* __restrict__ ldG,
                                                       float* __restrict__ out) {
  __shared__ float A[D][132];          // final L (lower); upper junk
  __shared__ float V[D][129];          // Linv (lower), upper zeroed
  __shared__ float T[3][32][33];       // per-pair matmul temps
  __shared__ float4 cb4[2][33];        // double-buffered pivot column (unscaled)
  __shared__ float dgl[D];             // pivots d_j
  __shared__ float invd[132];          // rsqrt(d_c) = 1/L_cc
  const int tid = threadIdx.x;         // row r
  const int k = blockIdx.x;
  const float* S = sigma + (size_t)k * D * D;

  if (k == 0 && tid == 0) out[0] = 0.f;

  // row r of sigma into registers (1MB total across 16 blocks; latency amortized by unroll)
  float4 a[32];
#pragma unroll
  for (int q = 0; q < 32; ++q)
    a[q] = *reinterpret_cast<const float4*>(&S[(size_t)tid * D + 4 * q]);

  for (int t = tid; t < D * D; t += 128) V[t >> 7][t & 127] = 0.f;

  reinterpret_cast<float*>(cb4[0])[tid] = a[0].x;   // publish column 0 (unscaled)
  float ldacc = 0.f;
  __syncthreads();

#pragma unroll
  for (int j = 0; j < D; ++j) {
    const int jq = j >> 2, je = j & 3;
    const float d = reinterpret_cast<const float*>(cb4[j & 1])[j];  // broadcast pivot
    ldacc += logf(d);
    const float aj = (je == 0) ? a[jq].x : (je == 1) ? a[jq].y : (je == 2) ? a[jq].z : a[jq].w;
    const float s = -aj * (1.0f / d);
#pragma unroll
    for (int q = jq; q < 32; ++q) {
      float4 cv = cb4[j & 1][q];                    // broadcast b128 read
      if (q == jq) {                                // static boundary mask: zero c <= j
        cv.x = 0.f;
        if (je >= 1) cv.y = 0.f;
        if (je >= 2) cv.z = 0.f;
        if (je >= 3) cv.w = 0.f;
      }
      a[q].x = fmaf(s, cv.x, a[q].x);
      a[q].y = fmaf(s, cv.y, a[q].y);
      a[q].z = fmaf(s, cv.z, a[q].z);
      a[q].w = fmaf(s, cv.w, a[q].w);
    }
    if (tid == 0) dgl[j] = d;
    if (j < D - 1) {
      const int nq = (j + 1) >> 2, ne = (j + 1) & 3;
      const float av = (ne == 0) ? a[nq].x : (ne == 1) ? a[nq].y : (ne == 2) ? a[nq].z : a[nq].w;
      reinterpret_cast<float*>(cb4[(j + 1) & 1])[tid] = av;  // publish next column
      __syncthreads();
    }
  }
  __syncthreads();
  invd[tid] = rsqrtf(dgl[tid]);        // 1/L_cc
  if (tid == 0) ldG[k] = 0.5f * ldacc;
  __syncthreads();

  // write final L rows to LDS: A[r][c] = a[c] * rsqrt(d_c)  (upper stays junk, never read)
#pragma unroll
  for (int q = 0; q < 32; ++q) {
    const float4 iv = *reinterpret_cast<const float4*>(&invd[4 * q]);
    float4 w;
    w.x = a[q].x * iv.x; w.y = a[q].y * iv.y; w.z = a[q].z * iv.z; w.w = a[q].w * iv.w;
    *reinterpret_cast<float4*>(&A[tid][4 * q]) = w;
  }
  __syncthreads();

  // ---- blocked triangular inverse: 4 diag 32x32 blocks, col per thread (chain <= 32) ----
  {
    const int c = tid, bend = ((c >> 5) + 1) << 5;
    V[c][c] = invd[c];
    for (int r = c + 1; r < bend; ++r) {
      float s = 0.f;
      for (int p = c; p < r; ++p) s += A[r][p] * V[p][c];
      V[r][c] = -s * invd[r];
    }
  }

  // ---- off-diagonal blocks, 3 dependency levels, register-blocked matmuls ----
  for (int d = 1; d <= 3; ++d) {
    __syncthreads();
    const int npair = 4 - d;
    for (int q = tid; q < npair * 256; q += 128) {       // phase A: M = L*V into T
      const int pair = q >> 8;
      const int r = (q >> 3) & 31;
      const int c4 = (q & 7) << 2;
      const int i0 = (pair + d) << 5, j0 = pair << 5;
      float m0 = 0.f, m1 = 0.f, m2 = 0.f, m3 = 0.f;
      for (int p = 0; p < d * 32; ++p) {
        const float av = A[i0 + r][j0 + p];
        const float* vp = &V[j0 + p][j0 + c4];
        m0 = fmaf(av, vp[0], m0); m1 = fmaf(av, vp[1], m1);
        m2 = fmaf(av, vp[2], m2); m3 = fmaf(av, vp[3], m3);
      }
      T[pair][r][c4] = m0; T[pair][r][c4 + 1] = m1;
      T[pair][r][c4 + 2] = m2; T[pair][r][c4 + 3] = m3;
    }
    __syncthreads();
    for (int q = tid; q < npair * 256; q += 128) {       // phase B: V_ij = -V_ii * M
      const int pair = q >> 8;
      const int r = (q >> 3) & 31;
      const int c4 = (q & 7) << 2;
      const int i0 = (pair + d) << 5, j0 = pair << 5;
      float m0 = 0.f, m1 = 0.f, m2 = 0.f, m3 = 0.f;
      for (int p = 0; p <= r; ++p) {                     // V_ii lower-triangular
        const float av = V[i0 + r][i0 + p];
        const float* tp = &T[pair][p][c4];
        m0 = fmaf(av, tp[0], m0); m1 = fmaf(av, tp[1], m1);
        m2 = fmaf(av, tp[2], m2); m3 = fmaf(av, tp[3], m3);
      }
      V[i0 + r][j0 + c4] = -m0; V[i0 + r][j0 + c4 + 1] = -m1;
      V[i0 + r][j0 + c4 + 2] = -m2; V[i0 + r][j0 + c4 + 3] = -m3;
    }
  }
  __syncthreads();

  // Lmu[k][j] = sum_i Linv[j][i]*mu[k][i]  (V upper = 0 -> uniform loop)
  {
    const float* muk = mu + k * D;
    float s = 0.f;
    for (int i = 0; i < D; ++i) s = fmaf(V[tid][i], muk[i], s);
    LmuG[k * D + tid] = s;
  }
  // bf16 image of Linv, pre-swizzled so linear global_load_lds lands XOR-swizzled in LDS
  for (int t = tid; t < D * D; t += 128) {
    const int j = t >> 7, i = t & 127;
    WG[(size_t)k * D * D + j * D + (i ^ ((j & 7) << 3))] = f2bf(V[j][i]);
  }
}

__device__ __forceinline__ void stage_tile(const unsigned short* gsrc, unsigned short* lds, int tid) {
#pragma unroll
  for (int c = 0; c < 4; ++c) {
    const int off = c * 4096 + tid * 8;  // u16 units; 16B per lane
    __builtin_amdgcn_global_load_lds(
        (const __attribute__((address_space(1))) unsigned int*)(gsrc + off),
        (__attribute__((address_space(3))) unsigned int*)(lds + off), 16, 0, 0);
  }
}

// ---------------- Main: Z^T = Linv * x^T per state (MFMA), maha = ||Z - Lmu||^2 ----------------
// 512 threads = 8 waves (2 j-groups x 4 bt-groups), 256 points/block, grid = 512
__global__ __launch_bounds__(512, 2) void main_kernel(const float* __restrict__ x,
                                                      const float* __restrict__ probs,
                                                      const unsigned short* __restrict__ WG,
                                                      const float* __restrict__ LmuG,
                                                      const float* __restrict__ ldG,
                                                      float* __restrict__ out) {
  __shared__ unsigned short xbuf[256 * 128];        // 64 KB, XOR-swizzled bf16 x
  __shared__ unsigned short Albuf[2][128 * 128];    // 64 KB, double-buffered swizzled Linv
  __shared__ float Lm[NK * D];                      // 8 KB
  __shared__ unsigned short pT[256 * 17];           // 8.5 KB, bf16 probs (padded stride 17)
  __shared__ float mah2[2][2][256];                 // 8 KB
  __shared__ float ld_s[NK];
  __shared__ float red[256];

  const int tid = threadIdx.x;
  const int ln = tid & 63;
  const int wid = tid >> 6;
  const int jg = wid >> 2;        // 0..1 : which 64 of the 128 z-dims
  const int bg = wid & 3;         // 0..3 : which 64 of the 256 points
  const int l15 = ln & 15, lg = ln >> 4;
  const size_t p0 = (size_t)blockIdx.x * 256;

  // stage x tile: fp32 -> bf16, XOR-swizzled writes (coalesced float4 reads)
  for (int t = tid; t < 256 * 128 / 4; t += 512) {
    const float4 v = *reinterpret_cast<const float4*>(&x[p0 * D + (size_t)t * 4]);
    const int flat = t * 4, row = flat >> 7, col = flat & 127;
    ushort4 h;
    h.x = f2bf(v.x); h.y = f2bf(v.y); h.z = f2bf(v.z); h.w = f2bf(v.w);
    *reinterpret_cast<ushort4*>(&xbuf[row * 128 + (col ^ ((row & 7) << 3))]) = h;
  }
  for (int t = tid; t < 256 * 16; t += 512)
    pT[(t >> 4) * 17 + (t & 15)] = f2bf(probs[p0 * NK + t]);
  for (int t = tid; t < NK * D; t += 512) Lm[t] = LmuG[t];
  if (tid < NK) ld_s[tid] = ldG[tid];

  stage_tile(WG, &Albuf[0][0], tid);   // state 0 Linv tile
  __syncthreads();

  float vt = 117.62413225f;            // 0.5*D*ln(2*pi); sum_k p_k == 1

  const int sw = (l15 & 7) << 3;       // XOR swizzle term

  for (int k = 0; k < NK; ++k) {
    if (k < NK - 1) stage_tile(WG + (size_t)(k + 1) * D * D, &Albuf[(k + 1) & 1][0], tid);

    const unsigned short* Ab = &Albuf[k & 1][0];
    f32x4 acc[4][4];
#pragma unroll
    for (int m = 0; m < 4; ++m)
#pragma unroll
      for (int n = 0; n < 4; ++n) acc[m][n] = (f32x4){0.f, 0.f, 0.f, 0.f};

#pragma unroll
    for (int ks = 0; ks < 4; ++ks) {
      const int kbs = (ks * 32 + lg * 8) ^ sw;
      bf16x8 av[4], bv[4];
#pragma unroll
      for (int m = 0; m < 4; ++m) {
        const int arow = jg * 64 + m * 16 + l15;
        av[m] = *reinterpret_cast<const bf16x8*>(&Ab[arow * 128 + kbs]);
      }
#pragma unroll
      for (int n = 0; n < 4; ++n) {
        const int brow = bg * 64 + n * 16 + l15;
        bv[n] = *reinterpret_cast<const bf16x8*>(&xbuf[brow * 128 + kbs]);
      }
#pragma unroll
      for (int m = 0; m < 4; ++m)
#pragma unroll
        for (int n = 0; n < 4; ++n)
          acc[m][n] = __builtin_amdgcn_mfma_f32_16x16x32_bf16(av[m], bv[n], acc[m][n], 0, 0, 0);
    }

    // epilogue: maha partials, lane-local j-reduction then xor across lane groups
    float lmv[4][4];
    const int jb = jg * 64 + lg * 4;
#pragma unroll
    for (int m = 0; m < 4; ++m)
#pragma unroll
      for (int r = 0; r < 4; ++r) lmv[m][r] = Lm[k * D + jb + m * 16 + r];
#pragma unroll
    for (int n = 0; n < 4; ++n) {
      float s = 0.f;
#pragma unroll
      for (int m = 0; m < 4; ++m)
#pragma unroll
        for (int r = 0; r < 4; ++r) {
          const float y = acc[m][n][r] - lmv[m][r];
          s = fmaf(y, y, s);
        }
      s += __shfl_xor(s, 16);
      s += __shfl_xor(s, 32);
      if (ln < 16) mah2[k & 1][jg][bg * 64 + n * 16 + ln] = s;
    }
    __syncthreads();   // also drains vmcnt -> next A tile resident

    if (tid < 256) {
      const float maha = mah2[k & 1][0][tid] + mah2[k & 1][1][tid];
      vt = fmaf(bf2f(pT[tid * 17 + k]), fmaf(0.5f, maha, ld_s[k]), vt);
    }
  }

  if (tid < 256) red[tid] = vt;
  __syncthreads();
  for (int s = 128; s > 0; s >>= 1) {
    if (tid < s) red[tid] += red[tid + s];
    __syncthreads();
  }
  if (tid == 0) atomicAdd(out, red[0] * (1.0f / 64.0f));
}

extern "C" void kernel_launch(void* const* d_in, const int* in_sizes, int n_in,
                              void* d_out, int out_size, void* d_ws, size_t ws_size,
                              hipStream_t stream) {
  const float* x     = (const float*)d_in[0];
  const float* mu    = (const float*)d_in[1];
  const float* sigma = (const float*)d_in[2];
  const float* probs = (const float*)d_in[3];
  float* out = (float*)d_out;

  unsigned short* WG = (unsigned short*)d_ws;          // 16*128*128 bf16 = 512 KB
  float* LmuG = (float*)(WG + (size_t)NK * D * D);     // 8 KB
  float* ldG  = LmuG + NK * D;                         // 64 B

  setup_kernel<<<NK, 128, 0, stream>>>(sigma, mu, WG, LmuG, ldG, out);
  main_kernel<<<BT / 256, 512, 0, stream>>>(x, probs, WG, LmuG, ldG, out);
}

// Round 7
// 295.982 us; speedup vs baseline: 1.5022x; 1.5022x over previous
//
#include <hip/hip_runtime.h>
#include <hip/hip_bf16.h>

#define D 128
#define NK 16
#define BT (64*2048)

typedef short bf16x8 __attribute__((ext_vector_type(8)));
typedef float f32x4 __attribute__((ext_vector_type(4)));

__device__ __forceinline__ unsigned short f2bf(float f) {
  unsigned u = __builtin_bit_cast(unsigned, f);
  unsigned r = (u + 0x7FFFu + ((u >> 16) & 1u)) >> 16;   // round-to-nearest-even
  return (unsigned short)r;
}
__device__ __forceinline__ float bf2f(unsigned short h) {
  unsigned u = ((unsigned)h) << 16;
  return __builtin_bit_cast(float, u);
}

// ---------------- Setup: blocked panel Cholesky -> logdet, Linv (bf16 image), Lmu ----------------
// R6 lesson: 128-deep unrolls get refused -> runtime-indexed reg arrays -> scratch (WRITE_SIZE
// +1MB). R7: 4 panels; 32x32 diag block factored wave-synchronously in registers via __shfl
// (zero LDS / zero barriers on the serial path); panel solve + SYRK are parallel phases with
// <=32-wide static unrolls. ~12 barriers total vs 256.
__global__ __launch_bounds__(128, 1) void setup_kernel(const float* __restrict__ sigma,
                                                       const float* __restrict__ mu,
                                                       unsigned short* __restrict__ WG,
                                                       float* __restrict__ LmuG,
                                                       float* __restrict__ ldG,
                                                       float* __restrict__ out) {
  __shared__ __align__(16) float A[D][132];     // sigma -> L (lower); upper junk
  __shared__ __align__(16) float V[D][129];     // Linv (lower), upper zeroed
  __shared__ __align__(16) float T[3][32][33];  // trinv temps; reused as Tp[96][32] panel buffer
  __shared__ __align__(16) float L11[32][33];   // current diag block (factored)
  __shared__ float dgl[D], invd[D];
  const int tid = threadIdx.x;
  const int k = blockIdx.x;
  const float* S = sigma + (size_t)k * D * D;

  if (k == 0 && tid == 0) out[0] = 0.f;

  for (int t = tid; t < D * D / 4; t += 128) {
    const int r = (4 * t) >> 7, c = (4 * t) & 127;
    *reinterpret_cast<float4*>(&A[r][c]) = *reinterpret_cast<const float4*>(&S[4 * t]);
  }
  for (int t = tid; t < D * D; t += 128) V[t >> 7][t & 127] = 0.f;
  __syncthreads();

  float* Tp = &T[0][0][0];                      // [96][32] view (3168 floats >= 3072)

  for (int p = 0; p < 4; ++p) {
    const int pe = p * 32;
    if (tid < 32) {
      // ---- wave-synchronous 32x32 Cholesky: lane r owns row r in w[32] ----
      float w[32];
#pragma unroll
      for (int q = 0; q < 8; ++q) {
        const float4 v = *reinterpret_cast<const float4*>(&A[pe + tid][pe + 4 * q]);
        w[4*q] = v.x; w[4*q+1] = v.y; w[4*q+2] = v.z; w[4*q+3] = v.w;
      }
      float mydiag = 1.f, myinv = 1.f;
#pragma unroll
      for (int j = 0; j < 32; ++j) {
        const float piv = __shfl(w[j], j);       // lane j's updated diagonal
        const float inv = rsqrtf(piv);
        if (tid == j) { w[j] = piv * inv; mydiag = piv * inv; myinv = inv; }
        else if (tid > j) w[j] *= inv;           // L[r][j]
        const float lrj = w[j];
#pragma unroll
        for (int c = j + 1; c < 32; ++c) {
          const float lcj = __shfl(w[j], c);     // L[c][j] from lane c
          if (tid >= c) w[c] = fmaf(-lrj, lcj, w[c]);
        }
      }
#pragma unroll
      for (int c = 0; c < 32; ++c) {
        L11[tid][c] = w[c];
        if (c <= tid) A[pe + tid][pe + c] = w[c];
      }
      dgl[pe + tid] = mydiag;
      invd[pe + tid] = myinv;                    // 1/L_cc
    }
    __syncthreads();
    if (p < 3) {
      const int r = tid;
      const bool act = (r >= pe + 32);
      float a[32];
      if (act) {
        // ---- panel solve: a <- L11^{-1} a (forward substitution, static unroll) ----
#pragma unroll
        for (int q = 0; q < 8; ++q) {
          const float4 v = *reinterpret_cast<const float4*>(&A[r][pe + 4 * q]);
          a[4*q] = v.x; a[4*q+1] = v.y; a[4*q+2] = v.z; a[4*q+3] = v.w;
        }
#pragma unroll
        for (int c = 0; c < 32; ++c) {
          float s = a[c];
#pragma unroll
          for (int q = 0; q < c; ++q) s = fmaf(-L11[c][q], a[q], s);
          a[c] = s * invd[pe + c];
        }
#pragma unroll
        for (int q = 0; q < 8; ++q) {
          const float4 v = {a[4*q], a[4*q+1], a[4*q+2], a[4*q+3]};
          *reinterpret_cast<float4*>(&A[r][pe + 4 * q]) = v;
          *reinterpret_cast<float4*>(&Tp[(r - pe - 32) * 32 + 4 * q]) = v;  // alias-free copy
        }
      }
      __syncthreads();
      if (act) {
        // ---- SYRK: A[r][c] -= sum_q l_r[q]*l_c[q], c in [pe+32, r]; reads Tp (no A alias) ----
        const int c40 = (pe + 32) >> 2, c41 = r >> 2;
        for (int c4 = c40; c4 <= c41; ++c4) {
          float dot0 = 0.f, dot1 = 0.f, dot2 = 0.f, dot3 = 0.f;
          const float* tb = &Tp[(4 * c4 - pe - 32) * 32];
#pragma unroll
          for (int q = 0; q < 8; ++q) {
            const float4 l0 = *reinterpret_cast<const float4*>(&tb[0 * 32 + 4 * q]);
            const float4 l1 = *reinterpret_cast<const float4*>(&tb[1 * 32 + 4 * q]);
            const float4 l2 = *reinterpret_cast<const float4*>(&tb[2 * 32 + 4 * q]);
            const float4 l3 = *reinterpret_cast<const float4*>(&tb[3 * 32 + 4 * q]);
            dot0 = fmaf(a[4*q], l0.x, fmaf(a[4*q+1], l0.y, fmaf(a[4*q+2], l0.z, fmaf(a[4*q+3], l0.w, dot0))));
            dot1 = fmaf(a[4*q], l1.x, fmaf(a[4*q+1], l1.y, fmaf(a[4*q+2], l1.z, fmaf(a[4*q+3], l1.w, dot1))));
            dot2 = fmaf(a[4*q], l2.x, fmaf(a[4*q+1], l2.y, fmaf(a[4*q+2], l2.z, fmaf(a[4*q+3], l2.w, dot2))));
            dot3 = fmaf(a[4*q], l3.x, fmaf(a[4*q+1], l3.y, fmaf(a[4*q+2], l3.z, fmaf(a[4*q+3], l3.w, dot3))));
          }
          float4 av = *reinterpret_cast<float4*>(&A[r][4 * c4]);
          if (4 * c4 + 0 <= r) av.x -= dot0;
          if (4 * c4 + 1 <= r) av.y -= dot1;
          if (4 * c4 + 2 <= r) av.z -= dot2;
          if (4 * c4 + 3 <= r) av.w -= dot3;
          *reinterpret_cast<float4*>(&A[r][4 * c4]) = av;
        }
      }
    }
    __syncthreads();
  }

  // ---- diag-block triangular inverse, registerized (reads A only; no store->load chain) ----
  {
    const int c = tid, ci = c & 31, b0 = (c >> 5) << 5;
    float v[32];
#pragma unroll
    for (int i = 0; i < 32; ++i) v[i] = 0.f;
#pragma unroll
    for (int i = 0; i < 32; ++i) {
      if (i == ci) v[i] = invd[c];
      else if (i > ci) {
        float s = 0.f;
#pragma unroll
        for (int q = 0; q < i; ++q)
          if (q >= ci) s = fmaf(A[b0 + i][b0 + q], v[q], s);
        v[i] = -s * invd[b0 + i];
      }
    }
#pragma unroll
    for (int i = 0; i < 32; ++i)
      if (i >= ci) V[b0 + i][c] = v[i];
  }

  // ---- off-diagonal Linv blocks, 3 dependency levels, register-blocked matmuls ----
  for (int d = 1; d <= 3; ++d) {
    __syncthreads();
    const int npair = 4 - d;
    for (int q = tid; q < npair * 256; q += 128) {       // phase A: M = L*V into T
      const int pair = q >> 8;
      const int r = (q >> 3) & 31;
      const int c4 = (q & 7) << 2;
      const int i0 = (pair + d) << 5, j0 = pair << 5;
      float m0 = 0.f, m1 = 0.f, m2 = 0.f, m3 = 0.f;
      for (int pp = 0; pp < d * 32; ++pp) {
        const float av = A[i0 + r][j0 + pp];
        const float* vp = &V[j0 + pp][j0 + c4];
        m0 = fmaf(av, vp[0], m0); m1 = fmaf(av, vp[1], m1);
        m2 = fmaf(av, vp[2], m2); m3 = fmaf(av, vp[3], m3);
      }
      T[pair][r][c4] = m0; T[pair][r][c4 + 1] = m1;
      T[pair][r][c4 + 2] = m2; T[pair][r][c4 + 3] = m3;
    }
    __syncthreads();
    for (int q = tid; q < npair * 256; q += 128) {       // phase B: V_ij = -V_ii * M
      const int pair = q >> 8;
      const int r = (q >> 3) & 31;
      const int c4 = (q & 7) << 2;
      const int i0 = (pair + d) << 5, j0 = pair << 5;
      float m0 = 0.f, m1 = 0.f, m2 = 0.f, m3 = 0.f;
      for (int pp = 0; pp <= r; ++pp) {                  // V_ii lower-triangular
        const float av = V[i0 + r][i0 + pp];
        const float* tp = &T[pair][pp][c4];
        m0 = fmaf(av, tp[0], m0); m1 = fmaf(av, tp[1], m1);
        m2 = fmaf(av, tp[2], m2); m3 = fmaf(av, tp[3], m3);
      }
      V[i0 + r][j0 + c4] = -m0; V[i0 + r][j0 + c4 + 1] = -m1;
      V[i0 + r][j0 + c4 + 2] = -m2; V[i0 + r][j0 + c4 + 3] = -m3;
    }
  }
  __syncthreads();

  // Lmu[k][j] = sum_i Linv[j][i]*mu[k][i]  (V upper = 0 -> uniform loop)
  {
    const float* muk = mu + k * D;
    float s = 0.f;
    for (int i = 0; i < D; ++i) s = fmaf(V[tid][i], muk[i], s);
    LmuG[k * D + tid] = s;
  }
  if (tid < 64) {                                        // wave-parallel logdet = sum log L_ii
    float s = logf(dgl[tid]) + logf(dgl[tid + 64]);
    s += __shfl_xor(s, 32); s += __shfl_xor(s, 16);
    s += __shfl_xor(s, 8);  s += __shfl_xor(s, 4);
    s += __shfl_xor(s, 2);  s += __shfl_xor(s, 1);
    if (tid == 0) ldG[k] = s;
  }
  // bf16 image of Linv, pre-swizzled so linear global_load_lds lands XOR-swizzled in LDS
  for (int t = tid; t < D * D; t += 128) {
    const int j = t >> 7, i = t & 127;
    WG[(size_t)k * D * D + j * D + (i ^ ((j & 7) << 3))] = f2bf(V[j][i]);
  }
}

__device__ __forceinline__ void stage_tile(const unsigned short* gsrc, unsigned short* lds, int tid) {
#pragma unroll
  for (int c = 0; c < 4; ++c) {
    const int off = c * 4096 + tid * 8;  // u16 units; 16B per lane
    __builtin_amdgcn_global_load_lds(
        (const __attribute__((address_space(1))) unsigned int*)(gsrc + off),
        (__attribute__((address_space(3))) unsigned int*)(lds + off), 16, 0, 0);
  }
}

// ---------------- Main: Z^T = Linv * x^T per state (MFMA), maha = ||Z - Lmu||^2 ----------------
// 512 threads = 8 waves (2 j-groups x 4 bt-groups), 256 points/block, grid = 512
__global__ __launch_bounds__(512, 2) void main_kernel(const float* __restrict__ x,
                                                      const float* __restrict__ probs,
                                                      const unsigned short* __restrict__ WG,
                                                      const float* __restrict__ LmuG,
                                                      const float* __restrict__ ldG,
                                                      float* __restrict__ out) {
  __shared__ unsigned short xbuf[256 * 128];        // 64 KB, XOR-swizzled bf16 x
  __shared__ unsigned short Albuf[2][128 * 128];    // 64 KB, double-buffered swizzled Linv
  __shared__ float Lm[NK * D];                      // 8 KB
  __shared__ unsigned short pT[256 * 17];           // 8.5 KB, bf16 probs (padded stride 17)
  __shared__ float mah2[2][2][256];                 // 8 KB
  __shared__ float ld_s[NK];
  __shared__ float red[256];

  const int tid = threadIdx.x;
  const int ln = tid & 63;
  const int wid = tid >> 6;
  const int jg = wid >> 2;        // 0..1 : which 64 of the 128 z-dims
  const int bg = wid & 3;         // 0..3 : which 64 of the 256 points
  const int l15 = ln & 15, lg = ln >> 4;
  const size_t p0 = (size_t)blockIdx.x * 256;

  // stage x tile: fp32 -> bf16, XOR-swizzled writes (coalesced float4 reads)
  for (int t = tid; t < 256 * 128 / 4; t += 512) {
    const float4 v = *reinterpret_cast<const float4*>(&x[p0 * D + (size_t)t * 4]);
    const int flat = t * 4, row = flat >> 7, col = flat & 127;
    ushort4 h;
    h.x = f2bf(v.x); h.y = f2bf(v.y); h.z = f2bf(v.z); h.w = f2bf(v.w);
    *reinterpret_cast<ushort4*>(&xbuf[row * 128 + (col ^ ((row & 7) << 3))]) = h;
  }
  for (int t = tid; t < 256 * 16; t += 512)
    pT[(t >> 4) * 17 + (t & 15)] = f2bf(probs[p0 * NK + t]);
  for (int t = tid; t < NK * D; t += 512) Lm[t] = LmuG[t];
  if (tid < NK) ld_s[tid] = ldG[tid];

  stage_tile(WG, &Albuf[0][0], tid);   // state 0 Linv tile
  __syncthreads();

  float vt = 117.62413225f;            // 0.5*D*ln(2*pi); sum_k p_k == 1

  const int sw = (l15 & 7) << 3;       // XOR swizzle term

  for (int k = 0; k < NK; ++k) {
    if (k < NK - 1) stage_tile(WG + (size_t)(k + 1) * D * D, &Albuf[(k + 1) & 1][0], tid);

    const unsigned short* Ab = &Albuf[k & 1][0];
    f32x4 acc[4][4];
#pragma unroll
    for (int m = 0; m < 4; ++m)
#pragma unroll
      for (int n = 0; n < 4; ++n) acc[m][n] = (f32x4){0.f, 0.f, 0.f, 0.f};

#pragma unroll
    for (int ks = 0; ks < 4; ++ks) {
      const int kbs = (ks * 32 + lg * 8) ^ sw;
      bf16x8 av[4], bv[4];
#pragma unroll
      for (int m = 0; m < 4; ++m) {
        const int arow = jg * 64 + m * 16 + l15;
        av[m] = *reinterpret_cast<const bf16x8*>(&Ab[arow * 128 + kbs]);
      }
#pragma unroll
      for (int n = 0; n < 4; ++n) {
        const int brow = bg * 64 + n * 16 + l15;
        bv[n] = *reinterpret_cast<const bf16x8*>(&xbuf[brow * 128 + kbs]);
      }
#pragma unroll
      for (int m = 0; m < 4; ++m)
#pragma unroll
        for (int n = 0; n < 4; ++n)
          acc[m][n] = __builtin_amdgcn_mfma_f32_16x16x32_bf16(av[m], bv[n], acc[m][n], 0, 0, 0);
    }

    // epilogue: maha partials, lane-local j-reduction then xor across lane groups
    float lmv[4][4];
    const int jb = jg * 64 + lg * 4;
#pragma unroll
    for (int m = 0; m < 4; ++m)
#pragma unroll
      for (int r = 0; r < 4; ++r) lmv[m][r] = Lm[k * D + jb + m * 16 + r];
#pragma unroll
    for (int n = 0; n < 4; ++n) {
      float s = 0.f;
#pragma unroll
      for (int m = 0; m < 4; ++m)
#pragma unroll
        for (int r = 0; r < 4; ++r) {
          const float y = acc[m][n][r] - lmv[m][r];
          s = fmaf(y, y, s);
        }
      s += __shfl_xor(s, 16);
      s += __shfl_xor(s, 32);
      if (ln < 16) mah2[k & 1][jg][bg * 64 + n * 16 + ln] = s;
    }
    __syncthreads();   // also drains vmcnt -> next A tile resident

    if (tid < 256) {
      const float maha = mah2[k & 1][0][tid] + mah2[k & 1][1][tid];
      vt = fmaf(bf2f(pT[tid * 17 + k]), fmaf(0.5f, maha, ld_s[k]), vt);
    }
  }

  if (tid < 256) red[tid] = vt;
  __syncthreads();
  for (int s = 128; s > 0; s >>= 1) {
    if (tid < s) red[tid] += red[tid + s];
    __syncthreads();
  }
  if (tid == 0) atomicAdd(out, red[0] * (1.0f / 64.0f));
}

extern "C" void kernel_launch(void* const* d_in, const int* in_sizes, int n_in,
                              void* d_out, int out_size, void* d_ws, size_t ws_size,
                              hipStream_t stream) {
  const float* x     = (const float*)d_in[0];
  const float* mu    = (const float*)d_in[1];
  const float* sigma = (const float*)d_in[2];
  const float* probs = (const float*)d_in[3];
  float* out = (float*)d_out;

  unsigned short* WG = (unsigned short*)d_ws;          // 16*128*128 bf16 = 512 KB
  float* LmuG = (float*)(WG + (size_t)NK * D * D);     // 8 KB
  float* ldG  = LmuG + NK * D;                         // 64 B

  setup_kernel<<<NK, 128, 0, stream>>>(sigma, mu, WG, LmuG, ldG, out);
  main_kernel<<<BT / 256, 512, 0, stream>>>(x, probs, WG, LmuG, ldG, out);
}

// Round 9
// 292.247 us; speedup vs baseline: 1.5214x; 1.0128x over previous
//
#include <hip/hip_runtime.h>
#include <hip/hip_bf16.h>

#define D 128
#define NK 16
#define BT (64*2048)

typedef short bf16x8 __attribute__((ext_vector_type(8)));
typedef float f32x4 __attribute__((ext_vector_type(4)));

__device__ __forceinline__ unsigned short f2bf(float f) {
  unsigned u = __builtin_bit_cast(unsigned, f);
  unsigned r = (u + 0x7FFFu + ((u >> 16) & 1u)) >> 16;   // round-to-nearest-even
  return (unsigned short)r;
}
__device__ __forceinline__ float bf2f(unsigned short h) {
  unsigned u = ((unsigned)h) << 16;
  return __builtin_bit_cast(float, u);
}

// zero flags + out each launch (graph-replay safe: d_ws is NOT re-poisoned between replays,
// so stale flags must be cleared by a prior dispatch in the same graph).
__global__ void zero_kernel(float* out, int* flags) {
  if (threadIdx.x == 0) out[0] = 0.f;
  if (threadIdx.x < NK) flags[threadIdx.x] = 0;
}

__device__ __forceinline__ void stage_tile(const unsigned short* gsrc, unsigned short* lds, int tid) {
#pragma unroll
  for (int c = 0; c < 4; ++c) {
    const int off = c * 4096 + tid * 8;  // u16 units; 16B per lane (512 threads)
    __builtin_amdgcn_global_load_lds(
        (const __attribute__((address_space(1))) unsigned int*)(gsrc + off),
        (__attribute__((address_space(3))) unsigned int*)(lds + off), 16, 0, 0);
  }
}

// LDS overlay (single 156224 B block, 1 block/CU):
//   main view : xbuf[0,65536) Albuf0[65536,98304) Albuf1[98304,131072) Lm[131072,139264)
//               pT[139264,147968) mah2/red[147968,156160) ld_s[156160,156224)
//   setup view: A[0,67584) V[67584,133632) T[133632,146304) L11[146304,150528)
//               dgl[150528,151040) invd[151040,151552)
#define SMEM_BYTES 156224

// ---------------- fused: blocks 0..15 run setup for state k=blockIdx, then all blocks
// wait on flags and run the MFMA main loop over 2 tiles of 256 points each ----------------
__global__ __launch_bounds__(512, 1) void fused_kernel(const float* __restrict__ x,
                                                       const float* __restrict__ probs,
                                                       const float* __restrict__ sigma,
                                                       const float* __restrict__ mu,
                                                       unsigned short* __restrict__ WG,
                                                       float* __restrict__ LmuG,
                                                       float* __restrict__ ldG,
                                                       int* __restrict__ flags,
                                                       float* __restrict__ out) {
  __shared__ __align__(16) char smem[SMEM_BYTES];
  const int tid = threadIdx.x;

  // ================= setup prologue (blocks 0..15) =================
  if (blockIdx.x < NK) {
    const int k = blockIdx.x;
    float (*A)[132]    = reinterpret_cast<float(*)[132]>(smem);
    float (*V)[129]    = reinterpret_cast<float(*)[129]>(smem + 67584);
    float (*T)[32][33] = reinterpret_cast<float(*)[32][33]>(smem + 133632);
    float (*L11)[33]   = reinterpret_cast<float(*)[33]>(smem + 146304);
    float* dgl  = reinterpret_cast<float*>(smem + 150528);
    float* invd = reinterpret_cast<float*>(smem + 151040);
    float* Tp   = reinterpret_cast<float*>(smem + 133632);   // [96][32] view
    const float* S = sigma + (size_t)k * D * D;

    for (int t = tid; t < D * D / 4; t += 512) {
      const int r = (4 * t) >> 7, c = (4 * t) & 127;
      *reinterpret_cast<float4*>(&A[r][c]) = *reinterpret_cast<const float4*>(&S[4 * t]);
    }
    for (int t = tid; t < D * D; t += 512) V[t >> 7][t & 127] = 0.f;
    __syncthreads();

    for (int p = 0; p < 4; ++p) {
      const int pe = p * 32;
      if (tid < 32) {
        // wave-synchronous 32x32 Cholesky: lane r owns row r in w[32]
        float w[32];
#pragma unroll
        for (int q = 0; q < 8; ++q) {
          const float4 v = *reinterpret_cast<const float4*>(&A[pe + tid][pe + 4 * q]);
          w[4*q] = v.x; w[4*q+1] = v.y; w[4*q+2] = v.z; w[4*q+3] = v.w;
        }
        float mydiag = 1.f, myinv = 1.f;
#pragma unroll
        for (int j = 0; j < 32; ++j) {
          const float piv = __shfl(w[j], j);
          const float inv = rsqrtf(piv);
          if (tid == j) { w[j] = piv * inv; mydiag = piv * inv; myinv = inv; }
          else if (tid > j) w[j] *= inv;
          const float lrj = w[j];
#pragma unroll
          for (int c = j + 1; c < 32; ++c) {
            const float lcj = __shfl(w[j], c);
            if (tid >= c) w[c] = fmaf(-lrj, lcj, w[c]);
          }
        }
#pragma unroll
        for (int c = 0; c < 32; ++c) {
          L11[tid][c] = w[c];
          if (c <= tid) A[pe + tid][pe + c] = w[c];
        }
        dgl[pe + tid] = mydiag;
        invd[pe + tid] = myinv;
      }
      __syncthreads();
      if (p < 3) {
        const int r = tid;
        const bool act = (tid < 128) && (r >= pe + 32);
        float a[32];
        if (act) {
          // panel solve: a <- L11^{-1} a (forward substitution, static unroll)
#pragma unroll
          for (int q = 0; q < 8; ++q) {
            const float4 v = *reinterpret_cast<const float4*>(&A[r][pe + 4 * q]);
            a[4*q] = v.x; a[4*q+1] = v.y; a[4*q+2] = v.z; a[4*q+3] = v.w;
          }
#pragma unroll
          for (int c = 0; c < 32; ++c) {
            float s = a[c];
#pragma unroll
            for (int q = 0; q < c; ++q) s = fmaf(-L11[c][q], a[q], s);
            a[c] = s * invd[pe + c];
          }
#pragma unroll
          for (int q = 0; q < 8; ++q) {
            const float4 v = {a[4*q], a[4*q+1], a[4*q+2], a[4*q+3]};
            *reinterpret_cast<float4*>(&A[r][pe + 4 * q]) = v;
            *reinterpret_cast<float4*>(&Tp[(r - pe - 32) * 32 + 4 * q]) = v;
          }
        }
        __syncthreads();
        if (act) {
          // SYRK: A[r][c] -= sum_q l_r[q]*l_c[q], reads Tp (no A alias)
          const int c40 = (pe + 32) >> 2, c41 = r >> 2;
          for (int c4 = c40; c4 <= c41; ++c4) {
            float dot0 = 0.f, dot1 = 0.f, dot2 = 0.f, dot3 = 0.f;
            const float* tb = &Tp[(4 * c4 - pe - 32) * 32];
#pragma unroll
            for (int q = 0; q < 8; ++q) {
              const float4 l0 = *reinterpret_cast<const float4*>(&tb[0 * 32 + 4 * q]);
              const float4 l1 = *reinterpret_cast<const float4*>(&tb[1 * 32 + 4 * q]);
              const float4 l2 = *reinterpret_cast<const float4*>(&tb[2 * 32 + 4 * q]);
              const float4 l3 = *reinterpret_cast<const float4*>(&tb[3 * 32 + 4 * q]);
              dot0 = fmaf(a[4*q], l0.x, fmaf(a[4*q+1], l0.y, fmaf(a[4*q+2], l0.z, fmaf(a[4*q+3], l0.w, dot0))));
              dot1 = fmaf(a[4*q], l1.x, fmaf(a[4*q+1], l1.y, fmaf(a[4*q+2], l1.z, fmaf(a[4*q+3], l1.w, dot1))));
              dot2 = fmaf(a[4*q], l2.x, fmaf(a[4*q+1], l2.y, fmaf(a[4*q+2], l2.z, fmaf(a[4*q+3], l2.w, dot2))));
              dot3 = fmaf(a[4*q], l3.x, fmaf(a[4*q+1], l3.y, fmaf(a[4*q+2], l3.z, fmaf(a[4*q+3], l3.w, dot3))));
            }
            float4 av = *reinterpret_cast<float4*>(&A[r][4 * c4]);
            if (4 * c4 + 0 <= r) av.x -= dot0;
            if (4 * c4 + 1 <= r) av.y -= dot1;
            if (4 * c4 + 2 <= r) av.z -= dot2;
            if (4 * c4 + 3 <= r) av.w -= dot3;
            *reinterpret_cast<float4*>(&A[r][4 * c4]) = av;
          }
        }
      }
      __syncthreads();
    }

    // diag-block triangular inverse, registerized
    if (tid < 128) {
      const int c = tid, ci = c & 31, b0 = (c >> 5) << 5;
      float v[32];
#pragma unroll
      for (int i = 0; i < 32; ++i) v[i] = 0.f;
#pragma unroll
      for (int i = 0; i < 32; ++i) {
        if (i == ci) v[i] = invd[c];
        else if (i > ci) {
          float s = 0.f;
#pragma unroll
          for (int q = 0; q < 32; ++q)
            if (q < i && q >= ci) s = fmaf(A[b0 + i][b0 + q], v[q], s);
          v[i] = -s * invd[b0 + i];
        }
      }
#pragma unroll
      for (int i = 0; i < 32; ++i)
        if (i >= ci) V[b0 + i][c] = v[i];
    }

    // off-diagonal Linv blocks, 3 dependency levels
    for (int d = 1; d <= 3; ++d) {
      __syncthreads();
      const int npair = 4 - d;
      for (int q = tid; q < npair * 256; q += 512) {       // phase A: M = L*V into T
        const int pair = q >> 8;
        const int r = (q >> 3) & 31;
        const int c4 = (q & 7) << 2;
        const int i0 = (pair + d) << 5, j0 = pair << 5;
        float m0 = 0.f, m1 = 0.f, m2 = 0.f, m3 = 0.f;
#pragma unroll 8
        for (int pp = 0; pp < d * 32; ++pp) {
          const float av = A[i0 + r][j0 + pp];
          const float* vp = &V[j0 + pp][j0 + c4];
          m0 = fmaf(av, vp[0], m0); m1 = fmaf(av, vp[1], m1);
          m2 = fmaf(av, vp[2], m2); m3 = fmaf(av, vp[3], m3);
        }
        T[pair][r][c4] = m0; T[pair][r][c4 + 1] = m1;
        T[pair][r][c4 + 2] = m2; T[pair][r][c4 + 3] = m3;
      }
      __syncthreads();
      for (int q = tid; q < npair * 256; q += 512) {       // phase B: V_ij = -V_ii * M
        const int pair = q >> 8;
        const int r = (q >> 3) & 31;
        const int c4 = (q & 7) << 2;
        const int i0 = (pair + d) << 5, j0 = pair << 5;
        float m0 = 0.f, m1 = 0.f, m2 = 0.f, m3 = 0.f;
#pragma unroll 8
        for (int pp = 0; pp <= r; ++pp) {
          const float av = V[i0 + r][i0 + pp];
          const float* tp = &T[pair][pp][c4];
          m0 = fmaf(av, tp[0], m0); m1 = fmaf(av, tp[1], m1);
          m2 = fmaf(av, tp[2], m2); m3 = fmaf(av, tp[3], m3);
        }
        V[i0 + r][j0 + c4] = -m0; V[i0 + r][j0 + c4 + 1] = -m1;
        V[i0 + r][j0 + c4 + 2] = -m2; V[i0 + r][j0 + c4 + 3] = -m3;
      }
    }
    __syncthreads();

    if (tid < 128) {
      const float* muk = mu + k * D;
      float s = 0.f;
      for (int i = 0; i < D; ++i) s = fmaf(V[tid][i], muk[i], s);
      LmuG[k * D + tid] = s;
    }
    if (tid < 64) {
      float s = logf(dgl[tid]) + logf(dgl[tid + 64]);
      s += __shfl_xor(s, 32); s += __shfl_xor(s, 16);
      s += __shfl_xor(s, 8);  s += __shfl_xor(s, 4);
      s += __shfl_xor(s, 2);  s += __shfl_xor(s, 1);
      if (tid == 0) ldG[k] = s;
    }
    for (int t = tid; t < D * D; t += 512) {
      const int j = t >> 7, i = t & 127;
      WG[(size_t)k * D * D + j * D + (i ^ ((j & 7) << 3))] = f2bf(V[j][i]);
    }
    __syncthreads();   // all stores issued+drained (barrier waits vmcnt)
    if (tid == 0) {
      __threadfence();  // agent release (L2 writeback) before publishing
      __hip_atomic_store(&flags[k], 1, __ATOMIC_RELEASE, __HIP_MEMORY_SCOPE_AGENT);
    }
    __syncthreads();
  }

  // ================= main phase (all 256 blocks, 2 tiles each) =================
  unsigned short* xbuf   = reinterpret_cast<unsigned short*>(smem);
  unsigned short* Albuf0 = reinterpret_cast<unsigned short*>(smem + 65536);
  unsigned short* Albuf1 = reinterpret_cast<unsigned short*>(smem + 98304);
  float* Lm   = reinterpret_cast<float*>(smem + 131072);
  unsigned short* pTl = reinterpret_cast<unsigned short*>(smem + 139264);
  float* mah2 = reinterpret_cast<float*>(smem + 147968);   // [2][2][256]
  float* red  = mah2;                                      // overlay, used at the very end
  float* ld_s = reinterpret_cast<float*>(smem + 156160);

  const int ln = tid & 63;
  const int wid = tid >> 6;
  const int jg = wid >> 2;        // 0..1 : which 64 of the 128 z-dims
  const int bg = wid & 3;         // 0..3 : which 64 of the 256 points
  const int l15 = ln & 15, lg = ln >> 4;
  const int sw = (l15 & 7) << 3;  // XOR swizzle term

  float vt = 0.f;

  for (int tile = 0; tile < 2; ++tile) {
    __syncthreads();   // LDS safe to overwrite (setup done / previous tile fully consumed)
    const size_t p0 = ((size_t)blockIdx.x * 2 + tile) * 256;

    // stage x tile: fp32 -> bf16, XOR-swizzled writes (overlaps setup on first tile)
    for (int t = tid; t < 256 * 128 / 4; t += 512) {
      const float4 v = *reinterpret_cast<const float4*>(&x[p0 * D + (size_t)t * 4]);
      const int flat = t * 4, row = flat >> 7, col = flat & 127;
      ushort4 h;
      h.x = f2bf(v.x); h.y = f2bf(v.y); h.z = f2bf(v.z); h.w = f2bf(v.w);
      *reinterpret_cast<ushort4*>(&xbuf[row * 128 + (col ^ ((row & 7) << 3))]) = h;
    }
    for (int t = tid; t < 256 * 16; t += 512)
      pTl[(t >> 4) * 17 + (t & 15)] = f2bf(probs[p0 * NK + t]);

    if (tile == 0) {
      if (tid < NK) {
        while (__hip_atomic_load(&flags[tid], __ATOMIC_ACQUIRE, __HIP_MEMORY_SCOPE_AGENT) == 0)
          __builtin_amdgcn_s_sleep(1);
      }
      __syncthreads();           // all states published; WG/LmuG/ldG readable
      for (int t = tid; t < NK * D; t += 512) Lm[t] = LmuG[t];
      if (tid < NK) ld_s[tid] = ldG[tid];
    }

    stage_tile(WG, Albuf0, tid);   // state 0 Linv tile
    __syncthreads();

    if (tid < 256) vt += 117.62413225f;   // 0.5*D*ln(2*pi) per point; sum_k p_k == 1

    for (int k = 0; k < NK; ++k) {
      if (k < NK - 1) stage_tile(WG + (size_t)(k + 1) * D * D, ((k + 1) & 1) ? Albuf1 : Albuf0, tid);

      const unsigned short* Ab = (k & 1) ? Albuf1 : Albuf0;
      f32x4 acc[4][4];
#pragma unroll
      for (int m = 0; m < 4; ++m)
#pragma unroll
        for (int n = 0; n < 4; ++n) acc[m][n] = (f32x4){0.f, 0.f, 0.f, 0.f};

#pragma unroll
      for (int ks = 0; ks < 4; ++ks) {
        const int kbs = (ks * 32 + lg * 8) ^ sw;
        bf16x8 av[4], bv[4];
#pragma unroll
        for (int m = 0; m < 4; ++m) {
          const int arow = jg * 64 + m * 16 + l15;
          av[m] = *reinterpret_cast<const bf16x8*>(&Ab[arow * 128 + kbs]);
        }
#pragma unroll
        for (int n = 0; n < 4; ++n) {
          const int brow = bg * 64 + n * 16 + l15;
          bv[n] = *reinterpret_cast<const bf16x8*>(&xbuf[brow * 128 + kbs]);
        }
#pragma unroll
        for (int m = 0; m < 4; ++m)
#pragma unroll
          for (int n = 0; n < 4; ++n)
            acc[m][n] = __builtin_amdgcn_mfma_f32_16x16x32_bf16(av[m], bv[n], acc[m][n], 0, 0, 0);
      }

      // epilogue: maha partials, lane-local j-reduction then xor across lane groups
      float lmv[4][4];
      const int jb = jg * 64 + lg * 4;
#pragma unroll
      for (int m = 0; m < 4; ++m)
#pragma unroll
        for (int r = 0; r < 4; ++r) lmv[m][r] = Lm[k * D + jb + m * 16 + r];
#pragma unroll
      for (int n = 0; n < 4; ++n) {
        float s = 0.f;
#pragma unroll
        for (int m = 0; m < 4; ++m)
#pragma unroll
          for (int r = 0; r < 4; ++r) {
            const float y = acc[m][n][r] - lmv[m][r];
            s = fmaf(y, y, s);
          }
        s += __shfl_xor(s, 16);
        s += __shfl_xor(s, 32);
        if (ln < 16) mah2[((k & 1) * 2 + jg) * 256 + bg * 64 + n * 16 + ln] = s;
      }
      __syncthreads();   // also drains vmcnt -> next A tile resident

      if (tid < 256) {
        const float maha = mah2[((k & 1) * 2 + 0) * 256 + tid] + mah2[((k & 1) * 2 + 1) * 256 + tid];
        vt = fmaf(bf2f(pTl[tid * 17 + k]), fmaf(0.5f, maha, ld_s[k]), vt);
      }
    }
  }

  __syncthreads();
  if (tid < 256) red[tid] = vt;
  __syncthreads();
  for (int s = 128; s > 0; s >>= 1) {
    if (tid < s) red[tid] += red[tid + s];
    __syncthreads();
  }
  if (tid == 0) atomicAdd(out, red[0] * (1.0f / 64.0f));
}

extern "C" void kernel_launch(void* const* d_in, const int* in_sizes, int n_in,
                              void* d_out, int out_size, void* d_ws, size_t ws_size,
                              hipStream_t stream) {
  const float* x     = (const float*)d_in[0];
  const float* mu    = (const float*)d_in[1];
  const float* sigma = (const float*)d_in[2];
  const float* probs = (const float*)d_in[3];
  float* out = (float*)d_out;

  unsigned short* WG = (unsigned short*)d_ws;          // 16*128*128 bf16 = 512 KB
  float* LmuG = (float*)(WG + (size_t)NK * D * D);     // 8 KB
  float* ldG  = LmuG + NK * D;                         // 64 B
  int* flags  = (int*)(ldG + NK);                      // 64 B

  zero_kernel<<<1, 64, 0, stream>>>(out, flags);
  fused_kernel<<<256, 512, 0, stream>>>(x, probs, sigma, mu, WG, LmuG, ldG, flags, out);
}

// Round 10
// 264.554 us; speedup vs baseline: 1.6807x; 1.1047x over previous
//
#include <hip/hip_runtime.h>
#include <hip/hip_bf16.h>

#define D 128
#define NK 16
#define BT (64*2048)
#define NTILES 512

typedef short bf16x8 __attribute__((ext_vector_type(8)));
typedef float f32x4 __attribute__((ext_vector_type(4)));

__device__ __forceinline__ unsigned short f2bf(float f) {
  unsigned u = __builtin_bit_cast(unsigned, f);
  unsigned r = (u + 0x7FFFu + ((u >> 16) & 1u)) >> 16;   // RTNE
  return (unsigned short)r;
}
__device__ __forceinline__ float bf2f(unsigned short h) {
  unsigned u = ((unsigned)h) << 16;
  return __builtin_bit_cast(float, u);
}
__device__ __forceinline__ unsigned cvtpk(float lo, float hi) {   // 2xf32 -> packed 2xbf16 (RTNE)
  unsigned r;
  asm volatile("v_cvt_pk_bf16_f32 %0, %1, %2" : "=v"(r) : "v"(lo), "v"(hi));
  return r;
}

__global__ void zero_kernel(float* out, int* flags, int* cnt) {
  if (threadIdx.x == 0) { out[0] = 0.f; cnt[0] = 0; }
  if (threadIdx.x < NK) flags[threadIdx.x] = 0;
}

__device__ __forceinline__ void stage_tile(const unsigned short* gsrc, unsigned short* lds, int tid) {
#pragma unroll
  for (int c = 0; c < 4; ++c) {
    const int off = c * 4096 + tid * 8;  // u16 units; 16B/lane, 512 threads
    __builtin_amdgcn_global_load_lds(
        (const __attribute__((address_space(1))) unsigned int*)(gsrc + off),
        (__attribute__((address_space(3))) unsigned int*)(lds + off), 16, 0, 0);
  }
}

// LDS overlay:
//  main : Albuf0[0,32768) Albuf1[32768,65536) pT[65536,74240) Lmb0[74240,74752)
//         Lmb1[74752,75264) ldb[75264,75272) tci[75272,75276) mah2/red[75280,79376)
//  setup: A[0,67584) V[67584,133632) T[133632,146304) L11[146304,150528)
//         dgl[150528,151040) invd[151040,151552)
#define SMEM_BYTES 151552

__global__ __launch_bounds__(512, 1) void fused_kernel(const float* __restrict__ x,
                                                       const float* __restrict__ probs,
                                                       const float* __restrict__ sigma,
                                                       const float* __restrict__ mu,
                                                       unsigned short* __restrict__ WG,
                                                       float* __restrict__ LmuG,
                                                       float* __restrict__ ldG,
                                                       int* __restrict__ flags,
                                                       int* __restrict__ cnt,
                                                       float* __restrict__ out) {
  __shared__ __align__(16) char smem[SMEM_BYTES];
  const int tid = threadIdx.x;

  // ================= setup prologue (blocks 0..15) =================
  if (blockIdx.x < NK) {
    const int k = blockIdx.x;
    float (*A)[132]    = reinterpret_cast<float(*)[132]>(smem);
    float (*V)[129]    = reinterpret_cast<float(*)[129]>(smem + 67584);
    float (*T)[32][33] = reinterpret_cast<float(*)[32][33]>(smem + 133632);
    float (*L11)[33]   = reinterpret_cast<float(*)[33]>(smem + 146304);
    float* dgl  = reinterpret_cast<float*>(smem + 150528);
    float* invd = reinterpret_cast<float*>(smem + 151040);
    float* Tp   = reinterpret_cast<float*>(smem + 133632);   // [96][32] view
    const float* S = sigma + (size_t)k * D * D;

    for (int t = tid; t < D * D / 4; t += 512) {
      const int r = (4 * t) >> 7, c = (4 * t) & 127;
      *reinterpret_cast<float4*>(&A[r][c]) = *reinterpret_cast<const float4*>(&S[4 * t]);
    }
    for (int t = tid; t < D * D; t += 512) V[t >> 7][t & 127] = 0.f;
    __syncthreads();

    for (int p = 0; p < 4; ++p) {
      const int pe = p * 32;
      if (tid < 32) {
        // wave-synchronous 32x32 Cholesky: lane r owns row r in w[32]
        float w[32];
#pragma unroll
        for (int q = 0; q < 8; ++q) {
          const float4 v = *reinterpret_cast<const float4*>(&A[pe + tid][pe + 4 * q]);
          w[4*q] = v.x; w[4*q+1] = v.y; w[4*q+2] = v.z; w[4*q+3] = v.w;
        }
        float mydiag = 1.f, myinv = 1.f;
#pragma unroll
        for (int j = 0; j < 32; ++j) {
          const float piv = __shfl(w[j], j);
          const float inv = rsqrtf(piv);
          if (tid == j) { w[j] = piv * inv; mydiag = piv * inv; myinv = inv; }
          else if (tid > j) w[j] *= inv;
          const float lrj = w[j];
#pragma unroll
          for (int c = j + 1; c < 32; ++c) {
            const float lcj = __shfl(w[j], c);
            if (tid >= c) w[c] = fmaf(-lrj, lcj, w[c]);
          }
        }
#pragma unroll
        for (int c = 0; c < 32; ++c) {
          L11[tid][c] = w[c];
          if (c <= tid) A[pe + tid][pe + c] = w[c];
        }
        dgl[pe + tid] = mydiag;
        invd[pe + tid] = myinv;
      }
      __syncthreads();
      if (p < 3) {
        {
          const int r = tid;
          if (tid < 128 && r >= pe + 32) {
            // panel solve: a <- L11^{-1} a (forward substitution, static unroll)
            float a[32];
#pragma unroll
            for (int q = 0; q < 8; ++q) {
              const float4 v = *reinterpret_cast<const float4*>(&A[r][pe + 4 * q]);
              a[4*q] = v.x; a[4*q+1] = v.y; a[4*q+2] = v.z; a[4*q+3] = v.w;
            }
#pragma unroll
            for (int c = 0; c < 32; ++c) {
              float s = a[c];
#pragma unroll
              for (int q = 0; q < c; ++q) s = fmaf(-L11[c][q], a[q], s);
              a[c] = s * invd[pe + c];
            }
#pragma unroll
            for (int q = 0; q < 8; ++q) {
              const float4 v = {a[4*q], a[4*q+1], a[4*q+2], a[4*q+3]};
              *reinterpret_cast<float4*>(&A[r][pe + 4 * q]) = v;
              *reinterpret_cast<float4*>(&Tp[(r - pe - 32) * 32 + 4 * q]) = v;
            }
          }
        }
        __syncthreads();
        {
          // SYRK parallelized: item = (row, quarter); quarter takes chunks c4 = base+q, +4, ...
          const int nr = 96 - 32 * p;
          if (tid < nr * 4) {
            const int r = pe + 32 + (tid % nr);
            const int quarter = tid / nr;
            float a2[32];
#pragma unroll
            for (int q = 0; q < 8; ++q) {
              const float4 v = *reinterpret_cast<const float4*>(&Tp[(r - pe - 32) * 32 + 4 * q]);
              a2[4*q] = v.x; a2[4*q+1] = v.y; a2[4*q+2] = v.z; a2[4*q+3] = v.w;
            }
            for (int c4 = ((pe + 32) >> 2) + quarter; c4 <= (r >> 2); c4 += 4) {
              float dot0 = 0.f, dot1 = 0.f, dot2 = 0.f, dot3 = 0.f;
              const float* tb = &Tp[(4 * c4 - pe - 32) * 32];
#pragma unroll
              for (int q = 0; q < 8; ++q) {
                const float4 l0 = *reinterpret_cast<const float4*>(&tb[0 * 32 + 4 * q]);
                const float4 l1 = *reinterpret_cast<const float4*>(&tb[1 * 32 + 4 * q]);
                const float4 l2 = *reinterpret_cast<const float4*>(&tb[2 * 32 + 4 * q]);
                const float4 l3 = *reinterpret_cast<const float4*>(&tb[3 * 32 + 4 * q]);
                dot0 = fmaf(a2[4*q], l0.x, fmaf(a2[4*q+1], l0.y, fmaf(a2[4*q+2], l0.z, fmaf(a2[4*q+3], l0.w, dot0))));
                dot1 = fmaf(a2[4*q], l1.x, fmaf(a2[4*q+1], l1.y, fmaf(a2[4*q+2], l1.z, fmaf(a2[4*q+3], l1.w, dot1))));
                dot2 = fmaf(a2[4*q], l2.x, fmaf(a2[4*q+1], l2.y, fmaf(a2[4*q+2], l2.z, fmaf(a2[4*q+3], l2.w, dot2))));
                dot3 = fmaf(a2[4*q], l3.x, fmaf(a2[4*q+1], l3.y, fmaf(a2[4*q+2], l3.z, fmaf(a2[4*q+3], l3.w, dot3))));
              }
              float4 av = *reinterpret_cast<float4*>(&A[r][4 * c4]);
              if (4 * c4 + 0 <= r) av.x -= dot0;
              if (4 * c4 + 1 <= r) av.y -= dot1;
              if (4 * c4 + 2 <= r) av.z -= dot2;
              if (4 * c4 + 3 <= r) av.w -= dot3;
              *reinterpret_cast<float4*>(&A[r][4 * c4]) = av;
            }
          }
        }
      }
      __syncthreads();
    }

    // diag-block triangular inverse, registerized
    if (tid < 128) {
      const int c = tid, ci = c & 31, b0 = (c >> 5) << 5;
      float v[32];
#pragma unroll
      for (int i = 0; i < 32; ++i) v[i] = 0.f;
#pragma unroll
      for (int i = 0; i < 32; ++i) {
        if (i == ci) v[i] = invd[c];
        else if (i > ci) {
          float s = 0.f;
#pragma unroll
          for (int q = 0; q < 32; ++q)
            if (q < i && q >= ci) s = fmaf(A[b0 + i][b0 + q], v[q], s);
          v[i] = -s * invd[b0 + i];
        }
      }
#pragma unroll
      for (int i = 0; i < 32; ++i)
        if (i >= ci) V[b0 + i][c] = v[i];
    }

    // off-diagonal Linv blocks, 3 dependency levels
    for (int d = 1; d <= 3; ++d) {
      __syncthreads();
      const int npair = 4 - d;
      for (int q = tid; q < npair * 256; q += 512) {       // phase A: M = L*V into T
        const int pair = q >> 8;
        const int r = (q >> 3) & 31;
        const int c4 = (q & 7) << 2;
        const int i0 = (pair + d) << 5, j0 = pair << 5;
        float m0 = 0.f, m1 = 0.f, m2 = 0.f, m3 = 0.f;
#pragma unroll 8
        for (int pp = 0; pp < d * 32; ++pp) {
          const float av = A[i0 + r][j0 + pp];
          const float* vp = &V[j0 + pp][j0 + c4];
          m0 = fmaf(av, vp[0], m0); m1 = fmaf(av, vp[1], m1);
          m2 = fmaf(av, vp[2], m2); m3 = fmaf(av, vp[3], m3);
        }
        T[pair][r][c4] = m0; T[pair][r][c4 + 1] = m1;
        T[pair][r][c4 + 2] = m2; T[pair][r][c4 + 3] = m3;
      }
      __syncthreads();
      for (int q = tid; q < npair * 256; q += 512) {       // phase B: V_ij = -V_ii * M
        const int pair = q >> 8;
        const int r = (q >> 3) & 31;
        const int c4 = (q & 7) << 2;
        const int i0 = (pair + d) << 5, j0 = pair << 5;
        float m0 = 0.f, m1 = 0.f, m2 = 0.f, m3 = 0.f;
#pragma unroll 8
        for (int pp = 0; pp <= r; ++pp) {
          const float av = V[i0 + r][i0 + pp];
          const float* tp = &T[pair][pp][c4];
          m0 = fmaf(av, tp[0], m0); m1 = fmaf(av, tp[1], m1);
          m2 = fmaf(av, tp[2], m2); m3 = fmaf(av, tp[3], m3);
        }
        V[i0 + r][j0 + c4] = -m0; V[i0 + r][j0 + c4 + 1] = -m1;
        V[i0 + r][j0 + c4 + 2] = -m2; V[i0 + r][j0 + c4 + 3] = -m3;
      }
    }
    __syncthreads();

    if (tid < 128) {
      const float* muk = mu + k * D;
      float s = 0.f;
      for (int i = 0; i < D; ++i) s = fmaf(V[tid][i], muk[i], s);
      LmuG[k * D + tid] = s;
    }
    if (tid < 64) {
      float s = logf(dgl[tid]) + logf(dgl[tid + 64]);
      s += __shfl_xor(s, 32); s += __shfl_xor(s, 16);
      s += __shfl_xor(s, 8);  s += __shfl_xor(s, 4);
      s += __shfl_xor(s, 2);  s += __shfl_xor(s, 1);
      if (tid == 0) ldG[k] = s;
    }
    // bf16 Linv image, pre-swizzled with (row&15) XOR so linear global_load_lds lands swizzled
    for (int t = tid; t < D * D; t += 512) {
      const int j = t >> 7, i = t & 127;
      WG[(size_t)k * D * D + j * D + (i ^ ((j & 15) << 3))] = f2bf(V[j][i]);
    }
    __syncthreads();   // all stores drained
    if (tid == 0) {
      __threadfence();
      __hip_atomic_store(&flags[k], 1, __ATOMIC_RELEASE, __HIP_MEMORY_SCOPE_AGENT);
    }
    __syncthreads();
  }

  // ================= main phase (all blocks, dynamic tiles) =================
  unsigned short* Albuf0 = reinterpret_cast<unsigned short*>(smem);
  unsigned short* Albuf1 = reinterpret_cast<unsigned short*>(smem + 32768);
  unsigned short* pTl    = reinterpret_cast<unsigned short*>(smem + 65536);
  float* Lmb0 = reinterpret_cast<float*>(smem + 74240);
  float* Lmb1 = reinterpret_cast<float*>(smem + 74752);
  float* ldb  = reinterpret_cast<float*>(smem + 75264);   // [2]
  int*   tci  = reinterpret_cast<int*>(smem + 75272);
  float* mah2 = reinterpret_cast<float*>(smem + 75280);   // [2][2][256]
  float* red  = mah2;

  const int ln = tid & 63;
  const int wid = tid >> 6;
  const int jg = wid >> 2;
  const int bg = wid & 3;
  const int l15 = ln & 15, lg = ln >> 4;

  float vt = 0.f;

  for (;;) {
    __syncthreads();                       // previous tile LDS fully consumed
    if (tid == 0) tci[0] = atomicAdd(cnt, 1);
    __syncthreads();
    const int tile = tci[0];
    if (tile >= NTILES) break;
    const size_t p0 = (size_t)tile * 256;

    // B-fragments: direct global fp32 -> bf16 registers, held across all 16 states
    bf16x8 bv[4][4];
#pragma unroll
    for (int n = 0; n < 4; ++n) {
      const float* xr = &x[(p0 + bg * 64 + n * 16 + l15) * D];
#pragma unroll
      for (int ks = 0; ks < 4; ++ks) {
        const float4 f0 = *reinterpret_cast<const float4*>(&xr[ks * 32 + lg * 8]);
        const float4 f1 = *reinterpret_cast<const float4*>(&xr[ks * 32 + lg * 8 + 4]);
        union { bf16x8 v; unsigned u[4]; } t;
        t.u[0] = cvtpk(f0.x, f0.y); t.u[1] = cvtpk(f0.z, f0.w);
        t.u[2] = cvtpk(f1.x, f1.y); t.u[3] = cvtpk(f1.z, f1.w);
        bv[ks][n] = t.v;
      }
    }
    for (int t = tid; t < 256 * 16; t += 512)
      pTl[(t >> 4) * 17 + (t & 15)] = f2bf(probs[p0 * NK + t]);

    if (tid < NK) {
      while (__hip_atomic_load(&flags[tid], __ATOMIC_ACQUIRE, __HIP_MEMORY_SCOPE_AGENT) == 0)
        __builtin_amdgcn_s_sleep(1);
    }
    __syncthreads();                       // flags seen + pT written
    stage_tile(WG, Albuf0, tid);
    if (tid < 128) Lmb0[tid] = LmuG[tid];
    if (tid == 256) ldb[0] = ldG[0];
    __syncthreads();                       // state-0 A/Lm/ld resident

    if (tid < 256) vt += 117.62413225f;    // 0.5*D*ln(2*pi); sum_k p_k == 1

    for (int k = 0; k < NK; ++k) {
      if (k < NK - 1) {
        stage_tile(WG + (size_t)(k + 1) * D * D, ((k + 1) & 1) ? Albuf1 : Albuf0, tid);
        if (tid < 128) (((k + 1) & 1) ? Lmb1 : Lmb0)[tid] = LmuG[(k + 1) * D + tid];
        if (tid == 256) ldb[(k + 1) & 1] = ldG[k + 1];
      }
      const unsigned short* Ab = (k & 1) ? Albuf1 : Albuf0;

      f32x4 acc[4][4];
#pragma unroll
      for (int m = 0; m < 4; ++m)
#pragma unroll
        for (int n = 0; n < 4; ++n) acc[m][n] = (f32x4){0.f, 0.f, 0.f, 0.f};

#pragma unroll
      for (int ks = 0; ks < 4; ++ks) {
        const int kbs = (ks * 32 + lg * 8) ^ (l15 << 3);   // (row&15) swizzle
        bf16x8 av[4];
#pragma unroll
        for (int m = 0; m < 4; ++m)
          av[m] = *reinterpret_cast<const bf16x8*>(&Ab[(jg * 64 + m * 16 + l15) * 128 + kbs]);
#pragma unroll
        for (int m = 0; m < 4; ++m)
#pragma unroll
          for (int n = 0; n < 4; ++n)
            acc[m][n] = __builtin_amdgcn_mfma_f32_16x16x32_bf16(av[m], bv[ks][n], acc[m][n], 0, 0, 0);
      }

      // epilogue: maha partials
      const float* LmC = (k & 1) ? Lmb1 : Lmb0;
      float lmv[4][4];
      const int jb = jg * 64 + lg * 4;
#pragma unroll
      for (int m = 0; m < 4; ++m)
#pragma unroll
        for (int r = 0; r < 4; ++r) lmv[m][r] = LmC[jb + m * 16 + r];
#pragma unroll
      for (int n = 0; n < 4; ++n) {
        float s = 0.f;
#pragma unroll
        for (int m = 0; m < 4; ++m)
#pragma unroll
          for (int r = 0; r < 4; ++r) {
            const float y = acc[m][n][r] - lmv[m][r];
            s = fmaf(y, y, s);
          }
        s += __shfl_xor(s, 16);
        s += __shfl_xor(s, 32);
        if (ln < 16) mah2[((k & 1) * 2 + jg) * 256 + bg * 64 + n * 16 + ln] = s;
      }
      __syncthreads();   // mah2 ready; staging k+1 drained

      if (tid < 256) {
        const float maha = mah2[((k & 1) * 2 + 0) * 256 + tid] + mah2[((k & 1) * 2 + 1) * 256 + tid];
        vt = fmaf(bf2f(pTl[tid * 17 + k]), fmaf(0.5f, maha, ldb[k & 1]), vt);
      }
    }
  }

  // final block reduction (mah2 region reused as red; all threads past loop barrier)
  if (tid < 256) red[tid] = vt;
  __syncthreads();
  for (int s = 128; s > 0; s >>= 1) {
    if (tid < s) red[tid] += red[tid + s];
    __syncthreads();
  }
  if (tid == 0) atomicAdd(out, red[0] * (1.0f / 64.0f));
}

extern "C" void kernel_launch(void* const* d_in, const int* in_sizes, int n_in,
                              void* d_out, int out_size, void* d_ws, size_t ws_size,
                              hipStream_t stream) {
  const float* x     = (const float*)d_in[0];
  const float* mu    = (const float*)d_in[1];
  const float* sigma = (const float*)d_in[2];
  const float* probs = (const float*)d_in[3];
  float* out = (float*)d_out;

  unsigned short* WG = (unsigned short*)d_ws;          // 512 KB
  float* LmuG = (float*)(WG + (size_t)NK * D * D);     // 8 KB
  float* ldG  = LmuG + NK * D;                         // 64 B
  int* flags  = (int*)(ldG + NK);                      // 64 B
  int* cnt    = flags + NK;                            // 4 B

  zero_kernel<<<1, 64, 0, stream>>>(out, flags, cnt);
  fused_kernel<<<256, 512, 0, stream>>>(x, probs, sigma, mu, WG, LmuG, ldG, flags, cnt, out);
}